// Round 5
// baseline (56079.602 us; speedup 1.0000x reference)
//
#include <hip/hip_runtime.h>
#include <hip/hip_bf16.h>
#include <hip/hip_cooperative_groups.h>
#include <math.h>

namespace cg = cooperative_groups;

#define T_ 256
#define B_ 128
#define VOC_ 256
#define EMB_ 512
#define N_ 1024
#define H_ 2048
#define WIN_ 32
#define OUT_EMB_ 1024

typedef _Float16 half8 __attribute__((ext_vector_type(8)));
typedef float f32x4 __attribute__((ext_vector_type(4)));

__device__ __forceinline__ float sigmoidf_(float x) { return 1.f / (1.f + expf(-x)); }

// ---------------------------------------------------------------------------
// Fused LSTM GEMM + gate epilogue (device body; proven in R4).
// WT gate-interleaved: row (4j+g) = original col g*1024+j, k-contiguous.
// 256 blocks: bn = bid&127 (32-col tiles), bm = bid>>7 (64-row tiles).
// BK=64, 2-deep register prefetch + double-buffered LDS.
// ---------------------------------------------------------------------------
__device__ __forceinline__
void lstm_gemm_body(_Float16 (*As)[64][72], _Float16 (*Bs)[32][72], int bid,
                    const _Float16* __restrict__ A0, int k0, int lda0,
                    const _Float16* __restrict__ A1, int k1, int lda1,
                    const _Float16* __restrict__ A2, int k2, int lda2,
                    const _Float16* __restrict__ WT, int Ktot,
                    const float* __restrict__ bias,
                    float* __restrict__ c, _Float16* __restrict__ hH,
                    _Float16* __restrict__ ringSlot, int ringHalf)
{
    const int tid = threadIdx.x;
    const int bn = bid & 127, bm = bid >> 7;
    const int lane = tid & 63, wid = tid >> 6;
    const int wm = wid >> 1, wn = wid & 1;
    const int l15 = lane & 15, l4 = lane >> 4;

    const int arow = tid >> 2, akh = (tid & 3) * 16;
    const int brow = tid >> 3, bkh = (tid & 7) * 8;
    const _Float16* Bg = WT + (size_t)(bn * 32 + brow) * Ktot;

    const int NIT = Ktot >> 6;           // 56 or 32 — always even

    f32x4 acc[2];
    acc[0] = (f32x4){0.f, 0.f, 0.f, 0.f};
    acc[1] = (f32x4){0.f, 0.f, 0.f, 0.f};

    half8 pa0A, pa1A, pbA, pa0B, pa1B, pbB;

    auto issue = [&](int it, half8& r0, half8& r1, half8& rb) {
        const int kb = it * 64;
        const _Float16* Ag; int so, ld;
        if (kb < k0)           { Ag = A0; so = 0;       ld = lda0; }
        else if (kb < k0 + k1) { Ag = A1; so = k0;      ld = lda1; }
        else                   { Ag = A2; so = k0 + k1; ld = lda2; }
        const _Float16* ap = Ag + (size_t)(bm * 64 + arow) * ld + (kb - so);
        r0 = *(const half8*)(ap + akh);
        r1 = *(const half8*)(ap + akh + 8);
        rb = *(const half8*)(Bg + kb + bkh);
    };
    auto wlds = [&](int buf, half8 r0, half8 r1, half8 rb) {
        *(half8*)&As[buf][arow][akh]     = r0;
        *(half8*)&As[buf][arow][akh + 8] = r1;
        *(half8*)&Bs[buf][brow][bkh]     = rb;
    };
    auto comp = [&](int buf) {
        #pragma unroll
        for (int ks = 0; ks < 2; ++ks) {
            half8 a0 = *(half8*)&As[buf][wm * 32 + l15][ks * 32 + l4 * 8];
            half8 a1 = *(half8*)&As[buf][wm * 32 + 16 + l15][ks * 32 + l4 * 8];
            half8 b0 = *(half8*)&Bs[buf][wn * 16 + l15][ks * 32 + l4 * 8];
            acc[0] = __builtin_amdgcn_mfma_f32_16x16x32_f16(a0, b0, acc[0], 0, 0, 0);
            acc[1] = __builtin_amdgcn_mfma_f32_16x16x32_f16(a1, b0, acc[1], 0, 0, 0);
        }
    };

    issue(0, pa0A, pa1A, pbA);
    issue(1, pa0B, pa1B, pbB);
    wlds(0, pa0A, pa1A, pbA);
    __syncthreads();

    for (int it = 0; it < NIT; it += 2) {
        comp(0);
        if (it + 2 < NIT) issue(it + 2, pa0A, pa1A, pbA);
        __syncthreads();
        wlds(1, pa0B, pa1B, pbB);
        __syncthreads();
        comp(1);
        if (it + 3 < NIT) issue(it + 3, pa0B, pa1B, pbB);
        __syncthreads();
        if (it + 2 < NIT) wlds(0, pa0A, pa1A, pbA);
        __syncthreads();
    }

    // fused LSTM epilogue; C/D layout: col = lane&15, row = (lane>>4)*4 + j
    const int cgl = bn * 32 + wn * 16 + l15;
    const bool owner = (cgl & 3) == 0;
    const int jglob = cgl >> 2;
    float bf = 0.f, bi = 0.f, bo_ = 0.f, bm_ = 0.f;
    if (owner) {
        bf  = bias[jglob];
        bi  = bias[1024 + jglob];
        bo_ = bias[2048 + jglob];
        bm_ = bias[3072 + jglob];
    }
    #pragma unroll
    for (int fm = 0; fm < 2; ++fm) {
        const int rbase = bm * 64 + wm * 32 + fm * 16 + l4 * 4;
        #pragma unroll
        for (int jr = 0; jr < 4; ++jr) {
            float v  = acc[fm][jr];
            float v1 = __shfl_xor(v, 1);
            float v2 = __shfl_xor(v, 2);
            float v3 = __shfl_xor(v, 3);
            if (owner) {
                const int r = rbase + jr;
                float zf = v + bf, zi = v1 + bi, zo = v2 + bo_, zm = v3 + bm_;
                float f = sigmoidf_(zf), ii = sigmoidf_(zi), o = sigmoidf_(zo);
                float m = tanhf(zm);
                const int ci = r * 1024 + jglob;
                float cn = c[ci] * f + m * ii;
                float hn = tanhf(cn) * o;
                c[ci] = cn;
                hH[ci] = (_Float16)hn;
                ringSlot[r * 2048 + ringHalf + jglob] = (_Float16)hn;
            }
        }
    }
}

// ---------------------------------------------------------------------------
// Attention body (one block per batch element b; LDS aliased onto GEMM bufs).
// ---------------------------------------------------------------------------
__device__ __forceinline__
void attn_body(float* hsl, float* pl, int b,
               const _Float16* __restrict__ ring, int t,
               _Float16* __restrict__ faH)
{
    const int tid = threadIdx.x;

    const _Float16* hs = ring + ((size_t)(t & 31) * B_ + b) * 2048;
    {
        half8 v = *(const half8*)(hs + tid * 8);
        #pragma unroll
        for (int e = 0; e < 8; ++e) hsl[tid * 8 + e] = (float)v[e];
    }
    __syncthreads();

    const int wv = tid >> 6, lane = tid & 63;
    #pragma unroll
    for (int w8 = 0; w8 < 8; ++w8) {
        const int w = wv * 8 + w8;
        const int tw = t - 31 + w;
        float s = 0.f;
        if (tw >= 0) {
            const _Float16* br = ring + ((size_t)(tw & 31) * B_ + b) * 2048;
            #pragma unroll
            for (int p2 = 0; p2 < 4; ++p2) {
                half8 v = *(const half8*)(br + p2 * 512 + lane * 8);
                const float* hp = &hsl[p2 * 512 + lane * 8];
                #pragma unroll
                for (int e = 0; e < 8; ++e) s += (float)v[e] * hp[e];
            }
        }
        #pragma unroll
        for (int off = 32; off > 0; off >>= 1) s += __shfl_xor(s, off);
        if (lane == 0) pl[w] = s;
    }
    __syncthreads();

    if (tid < 64) {
        float v = (lane < 32) ? pl[lane] : -3.4e38f;
        float m = v;
        #pragma unroll
        for (int off = 32; off > 0; off >>= 1) m = fmaxf(m, __shfl_xor(m, off));
        float e = (lane < 32) ? expf(v - m) : 0.f;
        float ssum = e;
        #pragma unroll
        for (int off = 32; off > 0; off >>= 1) ssum += __shfl_xor(ssum, off);
        if (lane < 32) pl[lane] = e / ssum;
    }
    __syncthreads();

    float a[8] = {0.f, 0.f, 0.f, 0.f, 0.f, 0.f, 0.f, 0.f};
    for (int w = 0; w < 32; ++w) {
        const int tw = t - 31 + w;
        if (tw >= 0) {
            const float pw = pl[w];
            half8 v = *(const half8*)(ring + ((size_t)(tw & 31) * B_ + b) * 2048 + tid * 8);
            #pragma unroll
            for (int e = 0; e < 8; ++e) a[e] += pw * (float)v[e];
        }
    }
    #pragma unroll
    for (int e = 0; e < 8; ++e) faH[b * 2048 + tid * 8 + e] = (_Float16)a[e];
}

// ---------------------------------------------------------------------------
// Persistent cooperative chunk: 32 recurrence steps, 3 grid syncs per step.
// Grid MUST be 256 blocks x 256 threads (one block per CU).
// ---------------------------------------------------------------------------
struct ChunkArgs {
    const _Float16* Ec;
    const _Float16* M0T;
    const _Float16* M1T;
    const float* B0;
    const float* B1;
    float* c0;
    float* c1;
    _Float16* h0H;      // 2 parity buffers, 131072 elems each
    _Float16* h1H;
    _Float16* faH;
    _Float16* ring;
    int t0;
};

__global__ __launch_bounds__(256)
void recurrence_chunk(ChunkArgs a)
{
    __shared__ _Float16 As[2][64][72];
    __shared__ _Float16 Bs[2][32][72];
    cg::grid_group grid = cg::this_grid();
    const int bid = blockIdx.x;

    for (int s = 0; s < 32; ++s) {
        const int t = a.t0 + s;
        const _Float16* Et = a.Ec + (size_t)s * B_ * EMB_;
        _Float16* ringSlot = a.ring + (size_t)(t & 31) * B_ * H_;
        _Float16* h0p = a.h0H + (size_t)(t & 1) * 131072;
        _Float16* h0c = a.h0H + (size_t)((t + 1) & 1) * 131072;
        _Float16* h1p = a.h1H + (size_t)(t & 1) * 131072;
        _Float16* h1c = a.h1H + (size_t)((t + 1) & 1) * 131072;

        // z0 = [E_t, fa, h0] @ M0 (K=3584), fused LSTM0
        lstm_gemm_body(As, Bs, bid, Et, 512, 512, a.faH, 2048, 2048,
                       h0p, 1024, 1024, a.M0T, 3584, a.B0, a.c0, h0c,
                       ringSlot, 0);
        grid.sync();

        // z1 = [h0, h1] @ M1 (K=2048), fused LSTM1
        lstm_gemm_body(As, Bs, bid, h0c, 1024, 1024, h1p, 1024, 1024,
                       nullptr, 0, 0, a.M1T, 2048, a.B1, a.c1, h1c,
                       ringSlot, 1024);
        grid.sync();

        // attention (blocks 0..127), writes faH for step t+1
        if (bid < 128)
            attn_body((float*)&As[0][0][0], (float*)&Bs[0][0][0], bid,
                      a.ring, t, a.faH);
        grid.sync();
    }
}

// ---------------------------------------------------------------------------
// Plain fp16 MFMA GEMM (emb + head).  mode 1: Cf=acc+bias; 2: relu->f16;
// 3: plain->f16.
// ---------------------------------------------------------------------------
__global__ __launch_bounds__(256)
void gemm_h(const _Float16* __restrict__ A0, int k0, int lda0,
            const _Float16* __restrict__ BT, int ldb,
            int N, int Ktot, int M,
            float* __restrict__ Cf, _Float16* __restrict__ Ch,
            const float* __restrict__ bias, int mode)
{
    __shared__ _Float16 As[64][40];
    __shared__ _Float16 Bs[64][40];

    const int tid = threadIdx.x;
    const int bn = blockIdx.x, bm = blockIdx.y;
    const int lane = tid & 63, wid = tid >> 6;
    const int wm = wid >> 1, wn = wid & 1;
    const int l15 = lane & 15, l4 = lane >> 4;
    const int ar = tid >> 2, ak = (tid & 3) * 8;

    f32x4 acc[2][2];
    #pragma unroll
    for (int i = 0; i < 2; ++i)
        #pragma unroll
        for (int j = 0; j < 2; ++j) acc[i][j] = (f32x4){0.f, 0.f, 0.f, 0.f};

    for (int kb = 0; kb < Ktot; kb += 32) {
        *(half8*)&As[ar][ak] =
            *(const half8*)(A0 + (size_t)(bm * 64 + ar) * lda0 + (kb + ak));
        *(half8*)&Bs[ar][ak] =
            *(const half8*)(BT + (size_t)(bn * 64 + ar) * ldb + (kb + ak));
        __syncthreads();

        half8 a0 = *(half8*)&As[wm * 32 + l15][l4 * 8];
        half8 a1 = *(half8*)&As[wm * 32 + 16 + l15][l4 * 8];
        half8 b0 = *(half8*)&Bs[wn * 32 + l15][l4 * 8];
        half8 b1 = *(half8*)&Bs[wn * 32 + 16 + l15][l4 * 8];
        acc[0][0] = __builtin_amdgcn_mfma_f32_16x16x32_f16(a0, b0, acc[0][0], 0, 0, 0);
        acc[0][1] = __builtin_amdgcn_mfma_f32_16x16x32_f16(a0, b1, acc[0][1], 0, 0, 0);
        acc[1][0] = __builtin_amdgcn_mfma_f32_16x16x32_f16(a1, b0, acc[1][0], 0, 0, 0);
        acc[1][1] = __builtin_amdgcn_mfma_f32_16x16x32_f16(a1, b1, acc[1][1], 0, 0, 0);
        __syncthreads();
    }

    const int colb = bn * 64 + wn * 32 + l15;
    const int rowb = bm * 64 + wm * 32 + l4 * 4;
    #pragma unroll
    for (int fm = 0; fm < 2; ++fm)
        #pragma unroll
        for (int fn = 0; fn < 2; ++fn) {
            const int cgc = colb + fn * 16;
            const int rg = rowb + fm * 16;
            const float bv = bias ? bias[cgc] : 0.f;
            #pragma unroll
            for (int j = 0; j < 4; ++j) {
                float v = acc[fm][fn][j] + bv;
                if (mode == 1)      Cf[(size_t)(rg + j) * N + cgc] = v;
                else if (mode == 2) Ch[(size_t)(rg + j) * N + cgc] = (_Float16)fmaxf(v, 0.f);
                else                Ch[(size_t)(rg + j) * N + cgc] = (_Float16)v;
            }
        }
}

// gatedH = (f16)(sigmoid(G) * hs)
__global__ __launch_bounds__(256)
void gate_epi(const _Float16* __restrict__ Gh, const _Float16* __restrict__ hsC,
              _Float16* __restrict__ gatedH)
{
    int idx = blockIdx.x * 256 + threadIdx.x;
    gatedH[idx] = (_Float16)(sigmoidf_((float)Gh[idx]) * (float)hsC[idx]);
}

// WT[n'][k] = (f16)W[k][n], zero-padded to Kp; gperm: n' = ((n&1023)<<2)|(n>>10)
__global__ __launch_bounds__(256)
void transpose_cast(const float* __restrict__ W, int K, int N,
                    _Float16* __restrict__ WT, int Kp, int gperm)
{
    __shared__ float tile[32][33];
    const int tx = threadIdx.x & 31, ty8 = threadIdx.x >> 5;
    const int k0 = blockIdx.y * 32, n0 = blockIdx.x * 32;
    for (int yy = ty8; yy < 32; yy += 8) {
        int k = k0 + yy;
        tile[yy][tx] = (k < K) ? W[(size_t)k * N + n0 + tx] : 0.f;
    }
    __syncthreads();
    for (int yy = ty8; yy < 32; yy += 8) {
        int n = n0 + yy;
        int nd = gperm ? (((n & 1023) << 2) | (n >> 10)) : n;
        WT[(size_t)nd * Kp + k0 + tx] = (_Float16)tile[tx][yy];
    }
}

// inpHc[r][0..287] = (f16)inp_chunk[r][0..257], zero-padded (4096 rows)
__global__ __launch_bounds__(256)
void cast_pad_inp(const float* __restrict__ inp, _Float16* __restrict__ inpH)
{
    int idx = blockIdx.x * 256 + threadIdx.x;
    int r = idx / 288, k = idx - r * 288;
    inpH[idx] = (k < 258) ? (_Float16)inp[(size_t)r * 258 + k] : (_Float16)0.f;
}

// ---------------------------------------------------------------------------
extern "C" void kernel_launch(void* const* d_in, const int* in_sizes, int n_in,
                              void* d_out, int out_size, void* d_ws, size_t ws_size,
                              hipStream_t stream)
{
    const float* inp  = (const float*)d_in[0];
    const float* embW = (const float*)d_in[1];
    const float* embB = (const float*)d_in[2];
    const float* M0   = (const float*)d_in[3];
    const float* B0   = (const float*)d_in[4];
    const float* M1   = (const float*)d_in[5];
    const float* B1   = (const float*)d_in[6];
    const float* Wg   = (const float*)d_in[7];
    const float* We   = (const float*)d_in[8];
    const float* be   = (const float*)d_in[9];
    const float* Wo   = (const float*)d_in[10];
    const float* bo   = (const float*)d_in[11];
    float* out = (float*)d_out;

    // ---- workspace (bytes), total ~127.4 MB ----
    char* p = (char*)d_ws;
    float*    c0    = (float*)p;      p += 524288;
    float*    c1    = (float*)p;      p += 524288;
    _Float16* h0H   = (_Float16*)p;   p += 524288;   // 2 parity buffers
    _Float16* h1H   = (_Float16*)p;   p += 524288;   // 2 parity buffers
    _Float16* faH   = (_Float16*)p;   p += 524288;
    char* zero_base = (char*)c0; size_t zero_bytes = (size_t)(p - zero_base);
    _Float16* inpHc = (_Float16*)p;   p += (size_t)4096 * 288 * 2;
    _Float16* embWT = (_Float16*)p;   p += (size_t)512 * 288 * 2;
    _Float16* M0T   = (_Float16*)p;   p += (size_t)4096 * 3584 * 2;
    _Float16* M1T   = (_Float16*)p;   p += (size_t)4096 * 2048 * 2;
    _Float16* WgT   = (_Float16*)p;   p += (size_t)2048 * 2048 * 2;
    _Float16* WeT   = (_Float16*)p;   p += (size_t)1024 * 2048 * 2;
    _Float16* WoT   = (_Float16*)p;   p += (size_t)256 * 1024 * 2;
    _Float16* Ec    = (_Float16*)p;   p += (size_t)4096 * 512 * 2;
    _Float16* ring  = (_Float16*)p;   p += (size_t)32 * B_ * H_ * 2;
    _Float16* Gh    = (_Float16*)p;   p += (size_t)4096 * 2048 * 2;
    _Float16* gatedH= (_Float16*)p;   p += (size_t)4096 * 2048 * 2;
    _Float16* RH    = (_Float16*)p;   p += (size_t)4096 * 1024 * 2;
    if ((size_t)(p - (char*)d_ws) > ws_size) return;

    hipMemsetAsync(zero_base, 0, zero_bytes, stream);

    // one-time weight prep (M0/M1 gate-interleaved)
    transpose_cast<<<dim3(16, 9),   256, 0, stream>>>(embW, 258, 512, embWT, 288, 0);
    transpose_cast<<<dim3(128, 112),256, 0, stream>>>(M0, 3584, 4096, M0T, 3584, 1);
    transpose_cast<<<dim3(128, 64), 256, 0, stream>>>(M1, 2048, 4096, M1T, 2048, 1);
    transpose_cast<<<dim3(64, 64),  256, 0, stream>>>(Wg, 2048, 2048, WgT, 2048, 0);
    transpose_cast<<<dim3(32, 64),  256, 0, stream>>>(We, 2048, 1024, WeT, 2048, 0);
    transpose_cast<<<dim3(8, 32),   256, 0, stream>>>(Wo, 1024, 256,  WoT, 1024, 0);

    for (int cch = 0; cch < 8; ++cch) {
        const int t0 = cch * 32;

        // embed this chunk
        cast_pad_inp<<<4608, 256, 0, stream>>>(inp + (size_t)t0 * B_ * 258, inpHc);
        gemm_h<<<dim3(8, 64), 256, 0, stream>>>(
            inpHc, 288, 288, embWT, 288, 512, 288, 4096, nullptr, Ec, embB, 3);

        // 32 recurrence steps in one cooperative launch
        ChunkArgs ca;
        ca.Ec = Ec; ca.M0T = M0T; ca.M1T = M1T; ca.B0 = B0; ca.B1 = B1;
        ca.c0 = c0; ca.c1 = c1; ca.h0H = h0H; ca.h1H = h1H;
        ca.faH = faH; ca.ring = ring; ca.t0 = t0;
        void* kp[] = { &ca };
        hipLaunchCooperativeKernel(recurrence_chunk, dim3(256), dim3(256),
                                   kp, 0, stream);

        // batched head over the chunk (ring slots 0..31 == steps t0..t0+31)
        gemm_h<<<dim3(32, 64), 256, 0, stream>>>(
            ring, 2048, 2048, WgT, 2048, 2048, 2048, 4096, nullptr, Gh, nullptr, 3);
        gate_epi<<<32768, 256, 0, stream>>>(Gh, ring, gatedH);
        gemm_h<<<dim3(16, 64), 256, 0, stream>>>(
            gatedH, 2048, 2048, WeT, 2048, 1024, 2048, 4096, nullptr, RH, be, 2);
        gemm_h<<<dim3(4, 64), 256, 0, stream>>>(
            RH, 1024, 1024, WoT, 1024, 256, 1024, 4096,
            out + (size_t)cch * 32 * B_ * VOC_, nullptr, bo, 1);
    }
}